// Round 1
// baseline (286.097 us; speedup 1.0000x reference)
//
#include <hip/hip_runtime.h>
#include <stdint.h>

// QuantumDeepField — MI355X (gfx950)
// Pipeline:
//   memset(M)                      zero Gram-matrix accumulator
//   k_prep   : c_n (per-(b,d) norm over A), z/q unpack, u/w fold of layer-1,
//              W2/W3 -> bf16 swizzled ws, out[b] = W_prop_b
//   k_corr   : systematic bf16-error correction at dens=0, adds G*corr to out
//   k_M      : M[b] = gto_un^T gto_un  (64x64 per molecule, f32, atomics)
//   k_cct    : S_mo = e^T M e ; cct[b][d][a] = c_n*inv_na*alpha (bf16 swizzled)
//   k_main   : per 128-row grid tile: gto -> mo (MFMA) -> density -> v1 ->
//              L2 (MFMA) -> L3 (MFMA) -> sum(v3 . wprop) -> atomicAdd out[b]

#define BB 8
#define GG 32768
#define AA 64
#define DD 128
#define EPSF 1e-12f

// ---- workspace layout (byte offsets) ----
#define WS_M    0u          // [B][64][64] f32 Gram (131072 B)
#define WS_ZQ   131072u     // [B][64][2] f32 {zeta, q-1} (4096 B)
#define WS_CN   135168u     // [B][64][128] f32 c_n (262144 B)
#define WS_UW   397312u     // u[128], w[128] f32 (1024 B)
#define WS_CCT  398336u     // [B][128][64] bf16 swizzled (131072 B)
#define WS_W2   529408u     // [128][128] bf16 swizzled (32768 B)
#define WS_W3   562176u     // [128][128] bf16 swizzled (32768 B) -> end 594944

typedef __attribute__((ext_vector_type(8))) short bf16x8;
typedef __attribute__((ext_vector_type(4))) float f32x4;

__device__ __forceinline__ unsigned short f2bf(float f) {
    union { float f; unsigned int u; } x; x.f = f;
    unsigned int u = x.u + 0x7FFFu + ((x.u >> 16) & 1u);
    return (unsigned short)(u >> 16);
}
__device__ __forceinline__ float bfround(float f) {
    union { float f; unsigned int u; } x; x.f = f;
    unsigned int u = x.u + 0x7FFFu + ((x.u >> 16) & 1u);
    x.u = u & 0xFFFF0000u;
    return x.f;
}

// ---------------- k_prep ----------------
__global__ __launch_bounds__(256)
void k_prep(const int* __restrict__ q, const int* __restrict__ ao,
            const float* __restrict__ coef, const float* __restrict__ zeta,
            const float* __restrict__ wpre_w, const float* __restrict__ wpre_b,
            const float* __restrict__ wfunc_w, const float* __restrict__ wfunc_b,
            const float* __restrict__ wprop_b, float* __restrict__ out,
            char* __restrict__ ws)
{
    int tid = blockIdx.x * 256 + threadIdx.x;
    if (tid < 32768) {
        // W2/W3 -> bf16, row-swizzled (byte ^= (row&7)<<4), row = output e
        int lsel = tid >> 14;           // 0 -> layer 1, 1 -> layer 2
        int idx = tid & 16383;
        int e = idx >> 7, dd = idx & 127;
        float v = wfunc_w[(lsel + 1) * 16384 + idx];
        unsigned short* dst = (unsigned short*)(ws + (lsel == 0 ? WS_W2 : WS_W3));
        int off = e * 256 + ((dd * 2) ^ ((e & 7) << 4));
        dst[off >> 1] = f2bf(v);
    } else if (tid < 33792) {
        // c_n: per-(b,d) L2 norm over A
        int i = tid - 32768;
        int b = i >> 7, dd = i & 127;
        float s = 0.f;
        for (int a = 0; a < AA; ++a) {
            float v = coef[ao[b * AA + a] * DD + dd];
            s += v * v;
        }
        float inv = 1.f / fmaxf(sqrtf(s), EPSF);
        float* cn = (float*)(ws + WS_CN);
        for (int a = 0; a < AA; ++a)
            cn[((size_t)b * AA + a) * DD + dd] = coef[ao[b * AA + a] * DD + dd] * inv;
    } else if (tid < 34304) {
        int i = tid - 33792;
        int b = i >> 6, a = i & 63;
        float* zq = (float*)(ws + WS_ZQ);
        zq[(b * AA + a) * 2 + 0] = zeta[ao[b * AA + a]];
        zq[(b * AA + a) * 2 + 1] = (float)q[b * AA + a];   // q-1 in {0,1,2}
    } else if (tid < 34432) {
        // fold layer-1: u = W1 @ w_pre ; w = W1 @ b_pre + b1
        int e = tid - 34304;
        float su = 0.f, sw = 0.f;
        for (int dd = 0; dd < DD; ++dd) {
            float wv = wfunc_w[e * DD + dd];
            su += wv * wpre_w[dd];
            sw += wv * wpre_b[dd];
        }
        float* uw = (float*)(ws + WS_UW);
        uw[e] = su;
        uw[128 + e] = sw + wfunc_b[e];
    } else if (tid < 34440) {
        out[tid - 34432] = wprop_b[0];
    }
}

// ---------------- k_corr : cancel systematic bf16 error ----------------
__global__ __launch_bounds__(128)
void k_corr(const float* __restrict__ wfunc_w, const float* __restrict__ wfunc_b,
            const float* __restrict__ wprop_w, float* __restrict__ out,
            char* __restrict__ ws)
{
    __shared__ float v1e[128], v1b[128], v2e[128], v2b[128];
    __shared__ float part[2];
    int t = threadIdx.x;
    const float* uw = (const float*)(ws + WS_UW);
    float w0 = uw[128 + t];
    float r = fmaxf(w0, 0.f);
    v1e[t] = r;
    v1b[t] = bfround(r);
    __syncthreads();
    float ze = wfunc_b[128 + t], zb = ze;
    for (int dd = 0; dd < 128; ++dd) {
        float wv = wfunc_w[16384 + t * 128 + dd];
        ze += wv * v1e[dd];
        zb += bfround(wv) * v1b[dd];
    }
    v2e[t] = fmaxf(ze, 0.f);
    v2b[t] = bfround(fmaxf(zb, 0.f));
    __syncthreads();
    float ye = wfunc_b[256 + t], yb = ye;
    for (int dd = 0; dd < 128; ++dd) {
        float wv = wfunc_w[32768 + t * 128 + dd];
        ye += wv * v2e[dd];
        yb += bfround(wv) * v2b[dd];
    }
    float wpv = wprop_w[t];
    float diff = (fmaxf(ye, 0.f) - fmaxf(yb, 0.f)) * wpv;
    #pragma unroll
    for (int m = 1; m < 64; m <<= 1) diff += __shfl_xor(diff, m);
    if ((t & 63) == 0) part[t >> 6] = diff;
    __syncthreads();
    if (t == 0) {
        float corr = (part[0] + part[1]) * (float)GG;
        #pragma unroll
        for (int b = 0; b < BB; ++b) atomicAdd(&out[b], corr);
    }
}

// ---------------- k_M : Gram matrix of unnormalized gto ----------------
__global__ __launch_bounds__(256)
void k_M(const float* __restrict__ dmat, char* __restrict__ ws)
{
    __shared__ float gs[32][64];
    const int b = blockIdx.y;
    const int gblk = blockIdx.x;       // 0..127, 256 rows each
    const int t = threadIdx.x;
    const int srow = t >> 3, scol = (t & 7) * 8;   // staging role
    const int ty = t >> 4, tx = t & 15;            // 4x4 tile role

    const float* zq = (const float*)(ws + WS_ZQ) + b * 128;
    float zz[8], qm[8];
    #pragma unroll
    for (int j = 0; j < 8; ++j) { zz[j] = zq[(scol + j) * 2]; qm[j] = zq[(scol + j) * 2 + 1]; }

    const float* dp = dmat + ((size_t)b * GG + (size_t)gblk * 256) * AA;
    float acc[4][4];
    #pragma unroll
    for (int i = 0; i < 4; ++i)
        #pragma unroll
        for (int j = 0; j < 4; ++j) acc[i][j] = 0.f;

    for (int ch = 0; ch < 8; ++ch) {
        const float* rp = dp + (size_t)(ch * 32 + srow) * AA + scol;
        float4 d0 = *(const float4*)rp;
        float4 d1 = *(const float4*)(rp + 4);
        float dv[8] = {d0.x, d0.y, d0.z, d0.w, d1.x, d1.y, d1.z, d1.w};
        float gv[8];
        #pragma unroll
        for (int j = 0; j < 8; ++j) {
            float tt = zz[j] * dv[j];
            float ex = __expf(-tt * tt);
            float pw = (qm[j] < 0.5f) ? 1.f : ((qm[j] < 1.5f) ? dv[j] : dv[j] * dv[j]);
            gv[j] = pw * ex;
        }
        __syncthreads();
        *(float4*)&gs[srow][scol]     = make_float4(gv[0], gv[1], gv[2], gv[3]);
        *(float4*)&gs[srow][scol + 4] = make_float4(gv[4], gv[5], gv[6], gv[7]);
        __syncthreads();
        #pragma unroll 4
        for (int g = 0; g < 32; ++g) {
            float4 va = *(const float4*)&gs[g][ty * 4];
            float4 vb = *(const float4*)&gs[g][tx * 4];
            float a4[4] = {va.x, va.y, va.z, va.w};
            float b4[4] = {vb.x, vb.y, vb.z, vb.w};
            #pragma unroll
            for (int i = 0; i < 4; ++i)
                #pragma unroll
                for (int j = 0; j < 4; ++j) acc[i][j] += a4[i] * b4[j];
        }
    }
    float* Mg = (float*)(ws + WS_M) + b * 4096;
    #pragma unroll
    for (int i = 0; i < 4; ++i)
        #pragma unroll
        for (int j = 0; j < 4; ++j)
            atomicAdd(&Mg[(ty * 4 + i) * 64 + tx * 4 + j], acc[i][j]);
}

// ---------------- k_cct : S_mo = e^T M e ; folded coeffs ----------------
__global__ __launch_bounds__(256)
void k_cct(const float* __restrict__ Ne, char* __restrict__ ws)
{
    __shared__ float M[64][64];
    __shared__ float e_s[128][65];
    __shared__ float inv_na[64];
    __shared__ float alpha[128];
    const int b = blockIdx.x, t = threadIdx.x;
    const float* Mg = (const float*)(ws + WS_M) + b * 4096;
    for (int i = t; i < 4096; i += 256) ((float*)M)[i] = Mg[i];
    __syncthreads();
    if (t < 64) inv_na[t] = 1.f / fmaxf(sqrtf(M[t][t]), EPSF);
    __syncthreads();
    const float* cn = (const float*)(ws + WS_CN) + (size_t)b * AA * DD;
    for (int i = t; i < 8192; i += 256) {
        int a = i >> 7, dd = i & 127;
        e_s[dd][a] = cn[a * DD + dd] * inv_na[a];
    }
    __syncthreads();
    const int d = t >> 1, half = t & 1;
    float y[32];
    #pragma unroll
    for (int j = 0; j < 32; ++j) y[j] = 0.f;
    for (int a = 0; a < 64; ++a) {
        float ea = e_s[d][a];
        const float4* Mr = (const float4*)&M[a][half * 32];
        #pragma unroll 8
        for (int j4 = 0; j4 < 8; ++j4) {
            float4 mv = Mr[j4];
            y[4 * j4 + 0] += ea * mv.x; y[4 * j4 + 1] += ea * mv.y;
            y[4 * j4 + 2] += ea * mv.z; y[4 * j4 + 3] += ea * mv.w;
        }
    }
    float s = 0.f;
    #pragma unroll 8
    for (int j = 0; j < 32; ++j) s += e_s[d][half * 32 + j] * y[j];
    s += __shfl_xor(s, 1);
    if (half == 0) alpha[d] = sqrtf(Ne[b] * (1.f / 128.f)) / fmaxf(sqrtf(s), EPSF);
    __syncthreads();
    unsigned short* cct = (unsigned short*)(ws + WS_CCT) + (size_t)b * 8192;
    for (int i = t; i < 8192; i += 256) {
        int dd = i >> 6, a = i & 63;
        float v = e_s[dd][a] * alpha[dd];
        int off = dd * 128 + ((a * 2) ^ ((dd & 7) << 4));
        cct[off >> 1] = f2bf(v);
    }
}

// ---------------- k_main ----------------
// dynamic LDS layout (bytes):
//   0      : W2 bf16 swz [128][256B]
//   32768  : W3 bf16 swz [128][256B]
//   65536  : cct bf16 swz [128][128B]
//   81920  : bufA 32KB  (gto [128][128B] -> v1 [128][256B] -> v2 [128][256B])
//   114688 : dens[128] f32 ; 115200 u ; 115712 w ; 116224 b2 ; 116736 b3 ;
//   117248 : wprop ; 117760 : zq[128] f32   -> total 118272
#define SMEM_MAIN 118272

__global__ __launch_bounds__(256, 1)
void k_main(const float* __restrict__ dmat, const float* __restrict__ wfunc_b,
            const float* __restrict__ wprop_w, float* __restrict__ out,
            char* __restrict__ ws)
{
    extern __shared__ char lds[];
    unsigned short* W2s = (unsigned short*)(lds);
    unsigned short* W3s = (unsigned short*)(lds + 32768);
    unsigned short* CTs = (unsigned short*)(lds + 65536);
    char* bufA = lds + 81920;
    float* dens = (float*)(lds + 114688);
    float* us   = (float*)(lds + 115200);
    float* wcs  = (float*)(lds + 115712);
    float* b2s  = (float*)(lds + 116224);
    float* b3s  = (float*)(lds + 116736);
    float* wps  = (float*)(lds + 117248);
    float* zqs  = (float*)(lds + 117760);

    const int t = threadIdx.x;
    const int b = blockIdx.x >> 5;
    const int blk = blockIdx.x & 31;

    {   // stage weights / constants
        const uint4* s2 = (const uint4*)(ws + WS_W2);
        const uint4* s3 = (const uint4*)(ws + WS_W3);
        const uint4* sc = (const uint4*)(ws + WS_CCT + (size_t)b * 16384u);
        uint4* d2 = (uint4*)W2s; uint4* d3 = (uint4*)W3s; uint4* dc = (uint4*)CTs;
        for (int i = t; i < 2048; i += 256) { d2[i] = s2[i]; d3[i] = s3[i]; }
        for (int i = t; i < 1024; i += 256) dc[i] = sc[i];
        const float* uw = (const float*)(ws + WS_UW);
        if (t < 128) {
            us[t]  = uw[t];
            wcs[t] = uw[128 + t];
            b2s[t] = wfunc_b[128 + t];
            b3s[t] = wfunc_b[256 + t];
            wps[t] = wprop_w[t];
            zqs[t] = ((const float*)(ws + WS_ZQ))[b * 128 + t];
        }
    }

    const int wv = t >> 6, l = t & 63;
    const int gsel = wv >> 1, dsel = wv & 1;
    const int lrow = l & 15, lk = l >> 4;
    const int srow = t >> 1, shalf = t & 1;

    const float* dbase = dmat + (size_t)b * GG * AA;
    float esum = 0.f;

    float4 pf[8];
    {
        const float4* p = (const float4*)(dbase + (size_t)(blk * 128 + srow) * AA + shalf * 32);
        #pragma unroll
        for (int k = 0; k < 8; ++k) pf[k] = p[k];
    }
    __syncthreads();

    for (int it = 0; it < 8; ++it) {
        // ---- phase 1: gto -> bufA (bf16, stride 128B, swizzled) ----
        #pragma unroll
        for (int c = 0; c < 4; ++c) {
            float v[8] = {pf[2*c].x, pf[2*c].y, pf[2*c].z, pf[2*c].w,
                          pf[2*c+1].x, pf[2*c+1].y, pf[2*c+1].z, pf[2*c+1].w};
            unsigned int wd[4];
            #pragma unroll
            for (int h = 0; h < 4; ++h) {
                unsigned short q2[2];
                #pragma unroll
                for (int jj = 0; jj < 2; ++jj) {
                    int j = 2 * h + jj;
                    int a = shalf * 32 + c * 8 + j;
                    float zz = zqs[2 * a], qmv = zqs[2 * a + 1];
                    float dv = v[j];
                    float tt = zz * dv;
                    float ex = __expf(-tt * tt);
                    float pw = (qmv < 0.5f) ? 1.f : ((qmv < 1.5f) ? dv : dv * dv);
                    q2[jj] = f2bf(pw * ex);
                }
                wd[h] = (unsigned int)q2[0] | ((unsigned int)q2[1] << 16);
            }
            int colB = shalf * 64 + c * 16;
            int off = srow * 128 + (colB ^ ((srow & 7) << 4));
            *(uint4*)(bufA + off) = make_uint4(wd[0], wd[1], wd[2], wd[3]);
        }
        if (t < 128) dens[t] = 0.f;

        // ---- phase 2: prefetch next tile's distances ----
        if (it < 7) {
            int nt = blk + 32 * (it + 1);
            const float4* p = (const float4*)(dbase + (size_t)(nt * 128 + srow) * AA + shalf * 32);
            #pragma unroll
            for (int k = 0; k < 8; ++k) pf[k] = p[k];
        }
        __syncthreads();

        // ---- phase 3: mo GEMM (K=64) + density ----
        {
            f32x4 acc[4][4];
            #pragma unroll
            for (int i = 0; i < 4; ++i)
                #pragma unroll
                for (int j = 0; j < 4; ++j) acc[i][j] = (f32x4){0.f, 0.f, 0.f, 0.f};
            #pragma unroll
            for (int kt = 0; kt < 2; ++kt) {
                bf16x8 af[4], bfv[4];
                int colB = kt * 64 + lk * 16;
                #pragma unroll
                for (int i = 0; i < 4; ++i) {
                    int gr = (gsel * 4 + i) * 16 + lrow;
                    af[i] = *(const bf16x8*)(bufA + gr * 128 + (colB ^ ((gr & 7) << 4)));
                }
                #pragma unroll
                for (int j = 0; j < 4; ++j) {
                    int dr = (dsel * 4 + j) * 16 + lrow;
                    bfv[j] = *(const bf16x8*)((const char*)CTs + dr * 128 + (colB ^ ((dr & 7) << 4)));
                }
                #pragma unroll
                for (int i = 0; i < 4; ++i)
                    #pragma unroll
                    for (int j = 0; j < 4; ++j)
                        acc[i][j] = __builtin_amdgcn_mfma_f32_16x16x32_bf16(af[i], bfv[j], acc[i][j], 0, 0, 0);
            }
            #pragma unroll
            for (int i = 0; i < 4; ++i) {
                float ds4[4] = {0.f, 0.f, 0.f, 0.f};
                #pragma unroll
                for (int j = 0; j < 4; ++j)
                    #pragma unroll
                    for (int r = 0; r < 4; ++r) { float m = acc[i][j][r]; ds4[r] += m * m; }
                #pragma unroll
                for (int r = 0; r < 4; ++r) {
                    float vv = ds4[r];
                    vv += __shfl_xor(vv, 1); vv += __shfl_xor(vv, 2);
                    vv += __shfl_xor(vv, 4); vv += __shfl_xor(vv, 8);
                    if (lrow == 0) atomicAdd(&dens[(gsel * 4 + i) * 16 + lk * 4 + r], vv);
                }
            }
        }
        __syncthreads();

        // ---- phase 4: v1 = relu(dens*u + w) -> bufA (bf16, stride 256B) ----
        {
            float dv = dens[srow];
            #pragma unroll
            for (int c = 0; c < 8; ++c) {
                unsigned int wd[4];
                #pragma unroll
                for (int h = 0; h < 4; ++h) {
                    unsigned short q2[2];
                    #pragma unroll
                    for (int jj = 0; jj < 2; ++jj) {
                        int di = shalf * 64 + c * 8 + 2 * h + jj;
                        q2[jj] = f2bf(fmaxf(dv * us[di] + wcs[di], 0.f));
                    }
                    wd[h] = (unsigned int)q2[0] | ((unsigned int)q2[1] << 16);
                }
                int colB = shalf * 128 + c * 16;
                int off = srow * 256 + (colB ^ ((srow & 7) << 4));
                *(uint4*)(bufA + off) = make_uint4(wd[0], wd[1], wd[2], wd[3]);
            }
        }
        __syncthreads();

        // ---- phase 5: L2 GEMM ----
        f32x4 acc2[4][4];
        {
            #pragma unroll
            for (int i = 0; i < 4; ++i)
                #pragma unroll
                for (int j = 0; j < 4; ++j) acc2[i][j] = (f32x4){0.f, 0.f, 0.f, 0.f};
            #pragma unroll
            for (int kt = 0; kt < 4; ++kt) {
                bf16x8 af[4], bfv[4];
                int colB = kt * 64 + lk * 16;
                #pragma unroll
                for (int i = 0; i < 4; ++i) {
                    int gr = (gsel * 4 + i) * 16 + lrow;
                    af[i] = *(const bf16x8*)(bufA + gr * 256 + (colB ^ ((gr & 7) << 4)));
                }
                #pragma unroll
                for (int j = 0; j < 4; ++j) {
                    int er = (dsel * 4 + j) * 16 + lrow;
                    bfv[j] = *(const bf16x8*)((const char*)W2s + er * 256 + (colB ^ ((er & 7) << 4)));
                }
                #pragma unroll
                for (int i = 0; i < 4; ++i)
                    #pragma unroll
                    for (int j = 0; j < 4; ++j)
                        acc2[i][j] = __builtin_amdgcn_mfma_f32_16x16x32_bf16(af[i], bfv[j], acc2[i][j], 0, 0, 0);
            }
        }
        __syncthreads();

        // ---- phase 6: v2 = relu(acc2 + b2) -> bufA ----
        #pragma unroll
        for (int j = 0; j < 4; ++j) {
            int e = (dsel * 4 + j) * 16 + lrow;
            float bias = b2s[e];
            #pragma unroll
            for (int i = 0; i < 4; ++i)
                #pragma unroll
                for (int r = 0; r < 4; ++r) {
                    int g = (gsel * 4 + i) * 16 + lk * 4 + r;
                    float vv = fmaxf(acc2[i][j][r] + bias, 0.f);
                    int off = g * 256 + ((e * 2) ^ ((g & 7) << 4));
                    *(unsigned short*)(bufA + off) = f2bf(vv);
                }
        }
        __syncthreads();

        // ---- phase 7: L3 GEMM ----
        f32x4 acc3[4][4];
        {
            #pragma unroll
            for (int i = 0; i < 4; ++i)
                #pragma unroll
                for (int j = 0; j < 4; ++j) acc3[i][j] = (f32x4){0.f, 0.f, 0.f, 0.f};
            #pragma unroll
            for (int kt = 0; kt < 4; ++kt) {
                bf16x8 af[4], bfv[4];
                int colB = kt * 64 + lk * 16;
                #pragma unroll
                for (int i = 0; i < 4; ++i) {
                    int gr = (gsel * 4 + i) * 16 + lrow;
                    af[i] = *(const bf16x8*)(bufA + gr * 256 + (colB ^ ((gr & 7) << 4)));
                }
                #pragma unroll
                for (int j = 0; j < 4; ++j) {
                    int er = (dsel * 4 + j) * 16 + lrow;
                    bfv[j] = *(const bf16x8*)((const char*)W3s + er * 256 + (colB ^ ((er & 7) << 4)));
                }
                #pragma unroll
                for (int i = 0; i < 4; ++i)
                    #pragma unroll
                    for (int j = 0; j < 4; ++j)
                        acc3[i][j] = __builtin_amdgcn_mfma_f32_16x16x32_bf16(af[i], bfv[j], acc3[i][j], 0, 0, 0);
            }
        }

        // ---- phase 8: v3 = relu(acc3 + b3); esum += v3 . wprop ----
        #pragma unroll
        for (int j = 0; j < 4; ++j) {
            int e = (dsel * 4 + j) * 16 + lrow;
            float bias = b3s[e], wpv = wps[e];
            #pragma unroll
            for (int i = 0; i < 4; ++i)
                #pragma unroll
                for (int r = 0; r < 4; ++r)
                    esum += fmaxf(acc3[i][j][r] + bias, 0.f) * wpv;
        }
        __syncthreads();   // protect bufA before next iteration's gto write
    }

    #pragma unroll
    for (int m = 1; m < 64; m <<= 1) esum += __shfl_xor(esum, m);
    if (l == 0) atomicAdd(&out[b], esum);
}

// ---------------- launcher ----------------
extern "C" void kernel_launch(void* const* d_in, const int* in_sizes, int n_in,
                              void* d_out, int out_size, void* d_ws, size_t ws_size,
                              hipStream_t stream)
{
    const float* dmat    = (const float*)d_in[0];
    const int*   q       = (const int*)d_in[1];
    const int*   ao      = (const int*)d_in[2];
    const float* Ne      = (const float*)d_in[3];
    const float* coef    = (const float*)d_in[4];
    const float* zeta    = (const float*)d_in[5];
    const float* wpre_w  = (const float*)d_in[6];
    const float* wpre_b  = (const float*)d_in[7];
    const float* wfunc_w = (const float*)d_in[8];
    const float* wfunc_b = (const float*)d_in[9];
    const float* wprop_w = (const float*)d_in[10];
    const float* wprop_b = (const float*)d_in[11];
    float* out = (float*)d_out;
    char*  ws  = (char*)d_ws;

    hipMemsetAsync(ws + WS_M, 0, 131072, stream);
    k_prep<<<135, 256, 0, stream>>>(q, ao, coef, zeta, wpre_w, wpre_b,
                                    wfunc_w, wfunc_b, wprop_b, out, ws);
    k_corr<<<1, 128, 0, stream>>>(wfunc_w, wfunc_b, wprop_w, out, ws);
    k_M<<<dim3(128, 8), 256, 0, stream>>>(dmat, ws);
    k_cct<<<8, 256, 0, stream>>>(Ne, ws);
    hipFuncSetAttribute((const void*)k_main,
                        hipFuncAttributeMaxDynamicSharedMemorySize, SMEM_MAIN);
    k_main<<<256, 256, SMEM_MAIN, stream>>>(dmat, wfunc_b, wprop_w, out, ws);
}